// Round 5
// baseline (770.703 us; speedup 1.0000x reference)
//
#include <hip/hip_runtime.h>
#include <cstdint>
#include <math.h>

#define N_     8192
#define D_     256
#define NLBL   128
#define TEMP_INV 14.285714285714286f
#define HARDK  10
#define THETA  0.16f
#define GCAP   256              // per-label list capacity (mean 64, max ~104)

#define RB     128              // rows per block (4 waves x 32)
#define NCHUNK 16
#define CHUNK  (N_ / NCHUNK)    // 512 cols per block
#define TILES  (CHUNK / 32)     // 16
#define SLOTS  8                // per-(row,chunk,kg) capacity (lambda ~1.34)

typedef __attribute__((ext_vector_type(8)))  short bf16x8;
typedef __attribute__((ext_vector_type(16))) float f32x16;

// ---------------- Threefry-2x32, key=(0,42): exact-match validated R1-R3 ----------------
__device__ __forceinline__ uint32_t rotl32(uint32_t x, int n) {
  return (x << n) | (x >> (32 - n));
}
__device__ uint32_t tf_bits(uint32_t idx) {
  uint32_t x0 = 0u, x1 = idx;
  const uint32_t k0 = 0u, k1 = 42u;
  const uint32_t k2 = k0 ^ k1 ^ 0x1BD11BDAu;
  x0 += k0; x1 += k1;
#define TFR(r) { x0 += x1; x1 = rotl32(x1, r); x1 ^= x0; }
  TFR(13) TFR(15) TFR(26) TFR(6)
  x0 += k1; x1 += k2 + 1u;
  TFR(17) TFR(29) TFR(16) TFR(24)
  x0 += k2; x1 += k0 + 2u;
  TFR(13) TFR(15) TFR(26) TFR(6)
  x0 += k0; x1 += k1 + 3u;
  TFR(17) TFR(29) TFR(16) TFR(24)
  x0 += k1; x1 += k2 + 4u;
  TFR(13) TFR(15) TFR(26) TFR(6)
  x0 += k2; x1 += k0 + 5u;
#undef TFR
  return x0 ^ x1;
}

__device__ __forceinline__ unsigned short f2bf(float x) {  // RNE
  uint32_t b = __float_as_uint(x);
  return (unsigned short)((b + 0x7FFFu + ((b >> 16) & 1u)) >> 16);
}

// ---------------- K1: inv_norm + bf16 z (4 rows/block) ----------------
__global__ __launch_bounds__(256) void prep_kernel(const float* __restrict__ feats,
                                                   float* __restrict__ inv_norm,
                                                   unsigned short* __restrict__ zbf) {
  const int i = blockIdx.x * 4 + (threadIdx.x >> 6);
  const int l = threadIdx.x & 63;
  float4 v = ((const float4*)feats)[(size_t)i * 64 + l];
  float ss = v.x * v.x + v.y * v.y + v.z * v.z + v.w * v.w;
#pragma unroll
  for (int o = 32; o; o >>= 1) ss += __shfl_xor(ss, o);
  float inv = 1.0f / fmaxf(sqrtf(ss), 1e-12f);
  if (l == 0) inv_norm[i] = inv;
  uint2 p;
  p.x = (uint32_t)f2bf(v.x * inv) | ((uint32_t)f2bf(v.y * inv) << 16);
  p.y = (uint32_t)f2bf(v.z * inv) | ((uint32_t)f2bf(v.w * inv) << 16);
  ((uint2*)zbf)[(size_t)i * 64 + l] = p;
}

// ---------------- K2: per-label bitmask + member list ----------------
__global__ __launch_bounds__(256) void group_kernel(const int* __restrict__ labels,
                                                    uint32_t* __restrict__ mask_g,
                                                    int* __restrict__ glist,
                                                    int* __restrict__ cnt_g) {
  const int b = blockIdx.x;
  const int tid = threadIdx.x, lane = tid & 63, wv = tid >> 6;
  __shared__ int lcnt;
  if (tid == 0) lcnt = 0;
  __syncthreads();
  for (int it = 0; it < N_; it += 256) {
    int col = it + tid;
    bool pred = (labels[col] == b);
    unsigned long long m = __ballot(pred);
    if (lane == 0) {
      int w0 = (it + wv * 64) >> 5;
      mask_g[b * 256 + w0]     = (uint32_t)m;
      mask_g[b * 256 + w0 + 1] = (uint32_t)(m >> 32);
    }
    if (pred) {
      int p = atomicAdd(&lcnt, 1);
      if (p < GCAP) glist[b * GCAP + p] = col;
    }
  }
  __syncthreads();
  if (tid == 0) cnt_g[b] = lcnt;
}

// ---------------- K3: MFMA sim + per-lane register-count threshold collect ----------------
__device__ __forceinline__ void stage_tile(const unsigned short* zbf, char (*AbK)[1024],
                                           int colT, int wid, int l, int kg) {
  const char* base = (const char*)zbf + ((size_t)(colT + (l & 31)) * (D_ * 2) + kg * 16);
#pragma unroll
  for (int q = 0; q < 4; ++q) {
    const int kk = wid * 4 + q;
    __builtin_amdgcn_global_load_lds(
        (const __attribute__((address_space(1))) void*)(base + kk * 32),
        (__attribute__((address_space(3))) void*)(&AbK[kk][0]), 16, 0, 0);
  }
}

__global__ __launch_bounds__(256) void collect_kernel(const unsigned short* __restrict__ zbf,
                                                      const int* __restrict__ labels,
                                                      const uint32_t* __restrict__ mask_g,
                                                      float* __restrict__ vals,
                                                      int* __restrict__ counts) {
  __shared__ char Ab[2][16][1024];  // [buf][kk][lane*16]

  const int tid = threadIdx.x;
  const int l = tid & 63, wid = tid >> 6;
  const int kg = l >> 5;
  const int bx = blockIdx.x;
  const int rc = bx & 63, cc = bx >> 6;
  const int row0 = rc * RB;
  const int col0 = cc * CHUNK;
  const int rowW = row0 + wid * 32 + (l & 31);
  const int lab_i = labels[rowW];
  const uint32_t* mrow = mask_g + lab_i * 256 + (col0 >> 5);

  // B fragments: 16 K-steps of this lane's row (64 VGPRs)
  bf16x8 bfrag[16];
  {
    const bf16x8* zr = (const bf16x8*)(zbf + (size_t)rowW * D_);
#pragma unroll
    for (int kk = 0; kk < 16; ++kk) bfrag[kk] = zr[kk * 2 + kg];
  }

  // PRIVATE slot block per (row, chunk, kg): the two lanes sharing rowW
  // (kg=0 covers cols 0-3 mod 8, kg=1 covers 4-7) never collide.
  float* vbase = vals + ((size_t)(rowW * NCHUNK + cc) * 2 + kg) * SLOTS;
  int pos = 0;

  stage_tile(zbf, Ab[0], col0, wid, l, kg);
  __syncthreads();

  int buf = 0;
  for (int t = 0; t < TILES; ++t) {
    if (t + 1 < TILES) stage_tile(zbf, Ab[buf ^ 1], col0 + (t + 1) * 32, wid, l, kg);
    const uint32_t wsh = mrow[t] >> (kg * 4);   // same-label bits for this tile

    f32x16 acc;
#pragma unroll
    for (int r = 0; r < 16; ++r) acc[r] = 0.f;
#pragma unroll
    for (int kk = 0; kk < 16; ++kk) {
      bf16x8 a = *(const bf16x8*)&Ab[buf][kk][l * 16];
      acc = __builtin_amdgcn_mfma_f32_32x32x16_bf16(a, bfrag[kk], acc, 0, 0, 0);
    }

    // lane owns row rowW; acc[r] = sim(rowW, col0 + t*32 + cpos + 4*kg)
#pragma unroll
    for (int r = 0; r < 16; ++r) {
      const int cpos = (r & 3) + 8 * (r >> 2);
      float c = acc[r];
      bool hit = (((wsh >> cpos) & 1u) == 0u) && (c > THETA);
      if (hit) {
        if (pos < SLOTS) vbase[pos] = c;
        ++pos;
      }
    }
    __syncthreads();
    buf ^= 1;
  }
  counts[(rowW * NCHUNK + cc) * 2 + kg] = pos;
}

// ---------------- K4: finalize (1 wave/row): pos pick + top-10 of collected + loss ----------------
__global__ __launch_bounds__(256) void finalize_kernel(
    const float* __restrict__ feats, const int* __restrict__ labels,
    const float* __restrict__ inv_norm,
    const int* __restrict__ glist, const int* __restrict__ cnt_g,
    const int* __restrict__ counts, const float* __restrict__ vals,
    float* __restrict__ li, int* __restrict__ valid) {
  const int row = blockIdx.x * 4 + (threadIdx.x >> 6);
  const int lane = threadIdx.x & 63;
  const int lab = labels[row];
  const int gc = cnt_g[lab];
  const int gn = gc < GCAP ? gc : GCAP;
  const float4* feats4 = (const float4*)feats;

  // --- positive pick: threefry argmax over same-label (excl self) ---
  uint32_t bk = 0u; int bj = -1;
  for (int e = lane; e < gn; e += 64) {
    int j = glist[lab * GCAP + e];
    if (j != row) {
      uint32_t key = tf_bits((uint32_t)row * (uint32_t)N_ + (uint32_t)j) >> 9;
      if (bj < 0 || key > bk || (key == bk && j < bj)) { bk = key; bj = j; }
    }
  }
#pragma unroll
  for (int o = 32; o; o >>= 1) {
    uint32_t ok = __shfl_xor(bk, o);
    int oj = __shfl_xor(bj, o);
    if (oj >= 0 && (bj < 0 || ok > bk || (ok == bk && oj < bj))) { bk = ok; bj = oj; }
  }

  // --- exact fp32 positive cosine ---
  float pc = 0.f;
  if (bj >= 0) {
    float4 a = feats4[(size_t)row * 64 + lane];
    float4 b = feats4[(size_t)bj * 64 + lane];
    float p = a.x * b.x + a.y * b.y + a.z * b.z + a.w * b.w;
#pragma unroll
    for (int o = 32; o; o >>= 1) p += __shfl_xor(p, o);
    pc = p * inv_norm[row] * inv_norm[bj];
  }

  // --- load collected candidates: 32 cells x 8 slots = 256, 4 per lane (coalesced) ---
  float vv[4];
  int ovf = 0;
#pragma unroll
  for (int q = 0; q < 4; ++q) {
    int s = lane + 64 * q;          // slot id 0..255
    int cell = s >> 3, wi = s & 7;  // cell = (chunk,kg) pair 0..31
    int c = counts[row * (NCHUNK * 2) + cell];
    ovf |= (c > SLOTS) ? 1 : 0;
    float val = vals[(size_t)row * (NCHUNK * 2 * SLOTS) + s];
    vv[q] = (wi < c) ? val : -INFINITY;
  }

  float num = expf(pc * TEMP_INV);
  float den = num;
  int got = 0;
#pragma unroll 1
  for (int it = 0; it < HARDK; ++it) {
    float lm4 = fmaxf(fmaxf(vv[0], vv[1]), fmaxf(vv[2], vv[3]));
    float wm = lm4;
#pragma unroll
    for (int o = 32; o; o >>= 1) wm = fmaxf(wm, __shfl_xor(wm, o));
    if (wm < -1e37f) break;
    den += expf(wm * TEMP_INV);
    ++got;
    unsigned long long b = __ballot(lm4 == wm);
    int fl = __ffsll((long long)b) - 1;
    if (lane == fl) {
      if (vv[0] == wm) vv[0] = -INFINITY;
      else if (vv[1] == wm) vv[1] = -INFINITY;
      else if (vv[2] == wm) vv[2] = -INFINITY;
      else vv[3] = -INFINITY;
    }
  }

  const int ndiff = N_ - gc;
  const bool vld = (bj >= 0) && (ndiff > 0);
  const int want = ndiff < HARDK ? ndiff : HARDK;

  // --- exact fallback (rare: slot overflow or <K above-threshold; guarantees exactness) ---
  if (vld && (__any(ovf) || got < want)) {
    float t[HARDK];
#pragma unroll
    for (int k = 0; k < HARDK; ++k) t[k] = -INFINITY;
    const float invr = inv_norm[row];
    for (int j = lane; j < N_; j += 64) {
      if (j == row || labels[j] == lab) continue;
      const float4* fr = feats4 + (size_t)row * 64;
      const float4* fj = feats4 + (size_t)j * 64;
      float p = 0.f;
      for (int d = 0; d < 64; ++d) {
        float4 x = fr[d], y = fj[d];
        p += x.x * y.x + x.y * y.y + x.z * y.z + x.w * y.w;
      }
      float c = p * invr * inv_norm[j];
#pragma unroll
      for (int q = 0; q < HARDK; ++q) {
        float hi = fmaxf(t[q], c);
        c = fminf(t[q], c);
        t[q] = hi;
      }
    }
    den = num;
#pragma unroll 1
    for (int it = 0; it < HARDK; ++it) {
      float lmx = t[0];
      float wm = lmx;
#pragma unroll
      for (int o = 32; o; o >>= 1) wm = fmaxf(wm, __shfl_xor(wm, o));
      if (wm < -1e37f) break;
      den += expf(wm * TEMP_INV);
      unsigned long long b = __ballot(lmx == wm);
      int fl = __ffsll((long long)b) - 1;
      if (lane == fl) {
#pragma unroll
        for (int q = 0; q < HARDK - 1; ++q) t[q] = t[q + 1];
        t[HARDK - 1] = -INFINITY;
      }
    }
  }

  float L = 0.f;
  if (vld) L = -logf(fmaxf(num / fmaxf(den, 1e-8f), 1e-8f));
  if (lane == 0) {
    li[row] = L;
    valid[row] = vld ? 1 : 0;
  }
}

// ---------------- K5: final mean ----------------
__global__ __launch_bounds__(256) void reduce_kernel(const float* __restrict__ li,
                                                     const int* __restrict__ valid,
                                                     float* __restrict__ out) {
  __shared__ float ssum[4];
  __shared__ int scnt[4];
  float s = 0.f; int c = 0;
  for (int i = threadIdx.x; i < N_; i += 256) { s += li[i]; c += valid[i]; }
#pragma unroll
  for (int o = 32; o; o >>= 1) { s += __shfl_down(s, o); c += __shfl_down(c, o); }
  if ((threadIdx.x & 63) == 0) { ssum[threadIdx.x >> 6] = s; scnt[threadIdx.x >> 6] = c; }
  __syncthreads();
  if (threadIdx.x == 0) {
    float S = 0.f; int C = 0;
    for (int w = 0; w < 4; ++w) { S += ssum[w]; C += scnt[w]; }
    out[0] = S / (float)(C > 0 ? C : 1);
  }
}

extern "C" void kernel_launch(void* const* d_in, const int* in_sizes, int n_in,
                              void* d_out, int out_size, void* d_ws, size_t ws_size,
                              hipStream_t stream) {
  const float* feats  = (const float*)d_in[0];
  const int*   labels = (const int*)d_in[1];
  float* out = (float*)d_out;

  char* w = (char*)d_ws;
  unsigned short* zbf = (unsigned short*)w;  w += (size_t)N_ * D_ * 2;        // 4 MB
  float* inv_norm = (float*)w;               w += (size_t)N_ * 4;
  uint32_t* mask_g = (uint32_t*)w;           w += (size_t)NLBL * 256 * 4;     // 128 KB
  int* glist = (int*)w;                      w += (size_t)NLBL * GCAP * 4;    // 128 KB
  int* cnt_g = (int*)w;                      w += (size_t)NLBL * 4;
  int* counts = (int*)w;                     w += (size_t)N_ * NCHUNK * 2 * 4;          // 1 MB
  float* vals = (float*)w;                   w += (size_t)N_ * NCHUNK * 2 * SLOTS * 4;  // 8.4 MB
  float* li_arr = (float*)w;                 w += (size_t)N_ * 4;
  int* valid_arr = (int*)w;                  w += (size_t)N_ * 4;

  hipLaunchKernelGGL(prep_kernel, dim3(N_ / 4), dim3(256), 0, stream, feats, inv_norm, zbf);
  hipLaunchKernelGGL(group_kernel, dim3(NLBL), dim3(256), 0, stream, labels, mask_g, glist, cnt_g);
  hipLaunchKernelGGL(collect_kernel, dim3(64 * NCHUNK), dim3(256), 0, stream,
                     zbf, labels, mask_g, vals, counts);
  hipLaunchKernelGGL(finalize_kernel, dim3(N_ / 4), dim3(256), 0, stream,
                     feats, labels, inv_norm, glist, cnt_g, counts, vals, li_arr, valid_arr);
  hipLaunchKernelGGL(reduce_kernel, dim3(1), dim3(256), 0, stream, li_arr, valid_arr, out);
}

// Round 6
// 95.172 us; speedup vs baseline: 8.0980x; 8.0980x over previous
//
#include <hip/hip_runtime.h>
#include <cstdint>
#include <math.h>

#define N_     8192
#define D_     256
#define NLBL   128
#define TEMP_INV 14.285714285714286f
#define HARDK  10
#define THETA  0.16f
#define GCAP   256              // per-label list capacity (mean 64, max ~104)

#define RB     128              // rows per block (4 waves x 32)
#define NCHUNK 16
#define CHUNK  (N_ / NCHUNK)    // 512 cols per block
#define TILES  (CHUNK / 32)     // 16
#define CSLOT  16               // per-(row,chunk) capacity, shared by kg0 (front) + kg1 (back)

typedef __attribute__((ext_vector_type(8)))  short bf16x8;
typedef __attribute__((ext_vector_type(16))) float f32x16;

// ---------------- Threefry-2x32, key=(0,42): exact-match validated R1-R5 ----------------
__device__ __forceinline__ uint32_t rotl32(uint32_t x, int n) {
  return (x << n) | (x >> (32 - n));
}
__device__ uint32_t tf_bits(uint32_t idx) {
  uint32_t x0 = 0u, x1 = idx;
  const uint32_t k0 = 0u, k1 = 42u;
  const uint32_t k2 = k0 ^ k1 ^ 0x1BD11BDAu;
  x0 += k0; x1 += k1;
#define TFR(r) { x0 += x1; x1 = rotl32(x1, r); x1 ^= x0; }
  TFR(13) TFR(15) TFR(26) TFR(6)
  x0 += k1; x1 += k2 + 1u;
  TFR(17) TFR(29) TFR(16) TFR(24)
  x0 += k2; x1 += k0 + 2u;
  TFR(13) TFR(15) TFR(26) TFR(6)
  x0 += k0; x1 += k1 + 3u;
  TFR(17) TFR(29) TFR(16) TFR(24)
  x0 += k1; x1 += k2 + 4u;
  TFR(13) TFR(15) TFR(26) TFR(6)
  x0 += k2; x1 += k0 + 5u;
#undef TFR
  return x0 ^ x1;
}

__device__ __forceinline__ unsigned short f2bf(float x) {  // RNE
  uint32_t b = __float_as_uint(x);
  return (unsigned short)((b + 0x7FFFu + ((b >> 16) & 1u)) >> 16);
}

// ---------------- K1: inv_norm + bf16 z (4 rows/block) ----------------
__global__ __launch_bounds__(256) void prep_kernel(const float* __restrict__ feats,
                                                   float* __restrict__ inv_norm,
                                                   unsigned short* __restrict__ zbf) {
  const int i = blockIdx.x * 4 + (threadIdx.x >> 6);
  const int l = threadIdx.x & 63;
  float4 v = ((const float4*)feats)[(size_t)i * 64 + l];
  float ss = v.x * v.x + v.y * v.y + v.z * v.z + v.w * v.w;
#pragma unroll
  for (int o = 32; o; o >>= 1) ss += __shfl_xor(ss, o);
  float inv = 1.0f / fmaxf(sqrtf(ss), 1e-12f);
  if (l == 0) inv_norm[i] = inv;
  uint2 p;
  p.x = (uint32_t)f2bf(v.x * inv) | ((uint32_t)f2bf(v.y * inv) << 16);
  p.y = (uint32_t)f2bf(v.z * inv) | ((uint32_t)f2bf(v.w * inv) << 16);
  ((uint2*)zbf)[(size_t)i * 64 + l] = p;
}

// ---------------- K2: per-label bitmask + member list ----------------
__global__ __launch_bounds__(256) void group_kernel(const int* __restrict__ labels,
                                                    uint32_t* __restrict__ mask_g,
                                                    int* __restrict__ glist,
                                                    int* __restrict__ cnt_g) {
  const int b = blockIdx.x;
  const int tid = threadIdx.x, lane = tid & 63, wv = tid >> 6;
  __shared__ int lcnt;
  if (tid == 0) lcnt = 0;
  __syncthreads();
  for (int it = 0; it < N_; it += 256) {
    int col = it + tid;
    bool pred = (labels[col] == b);
    unsigned long long m = __ballot(pred);
    if (lane == 0) {
      int w0 = (it + wv * 64) >> 5;
      mask_g[b * 256 + w0]     = (uint32_t)m;
      mask_g[b * 256 + w0 + 1] = (uint32_t)(m >> 32);
    }
    if (pred) {
      int p = atomicAdd(&lcnt, 1);
      if (p < GCAP) glist[b * GCAP + p] = col;
    }
  }
  __syncthreads();
  if (tid == 0) cnt_g[b] = lcnt;
}

// ---------------- K3: MFMA sim + threshold collect (front/back shared cell) ----------------
__device__ __forceinline__ void stage_tile(const unsigned short* zbf, char (*AbK)[1024],
                                           int colT, int wid, int l, int kg) {
  const char* base = (const char*)zbf + ((size_t)(colT + (l & 31)) * (D_ * 2) + kg * 16);
#pragma unroll
  for (int q = 0; q < 4; ++q) {
    const int kk = wid * 4 + q;
    __builtin_amdgcn_global_load_lds(
        (const __attribute__((address_space(1))) void*)(base + kk * 32),
        (__attribute__((address_space(3))) void*)(&AbK[kk][0]), 16, 0, 0);
  }
}

__global__ __launch_bounds__(256) void collect_kernel(const unsigned short* __restrict__ zbf,
                                                      const int* __restrict__ labels,
                                                      const uint32_t* __restrict__ mask_g,
                                                      float* __restrict__ vals,
                                                      int* __restrict__ counts) {
  __shared__ char Ab[2][16][1024];  // [buf][kk][lane*16]

  const int tid = threadIdx.x;
  const int l = tid & 63, wid = tid >> 6;
  const int kg = l >> 5;
  const int bx = blockIdx.x;
  const int rc = bx & 63, cc = bx >> 6;
  const int row0 = rc * RB;
  const int col0 = cc * CHUNK;
  const int rowW = row0 + wid * 32 + (l & 31);
  const int lab_i = labels[rowW];
  const uint32_t* mrow = mask_g + lab_i * 256 + (col0 >> 5);

  // B fragments: 16 K-steps of this lane's row (64 VGPRs)
  bf16x8 bfrag[16];
  {
    const bf16x8* zr = (const bf16x8*)(zbf + (size_t)rowW * D_);
#pragma unroll
    for (int kk = 0; kk < 16; ++kk) bfrag[kk] = zr[kk * 2 + kg];
  }

  // Shared 16-slot cell per (row, chunk); kg=0 fills from front, kg=1 from back.
  // Private register counts -> no atomics, no races while c0+c1 <= 16
  // (P ~ 4e-9 per cell; overflow detected in finalize -> exact fallback).
  float* vbase = vals + (size_t)rowW * (NCHUNK * CSLOT) + cc * CSLOT;
  int pos = 0;

  stage_tile(zbf, Ab[0], col0, wid, l, kg);
  __syncthreads();

  int buf = 0;
  for (int t = 0; t < TILES; ++t) {
    if (t + 1 < TILES) stage_tile(zbf, Ab[buf ^ 1], col0 + (t + 1) * 32, wid, l, kg);
    const uint32_t wsh = mrow[t] >> (kg * 4);   // same-label bits for this tile

    f32x16 acc;
#pragma unroll
    for (int r = 0; r < 16; ++r) acc[r] = 0.f;
#pragma unroll
    for (int kk = 0; kk < 16; ++kk) {
      bf16x8 a = *(const bf16x8*)&Ab[buf][kk][l * 16];
      acc = __builtin_amdgcn_mfma_f32_32x32x16_bf16(a, bfrag[kk], acc, 0, 0, 0);
    }

    // lane owns row rowW; acc[r] = sim(rowW, col0 + t*32 + cpos + 4*kg)
#pragma unroll
    for (int r = 0; r < 16; ++r) {
      const int cpos = (r & 3) + 8 * (r >> 2);
      float c = acc[r];
      bool hit = (((wsh >> cpos) & 1u) == 0u) && (c > THETA);
      if (hit) {
        if (pos < CSLOT) vbase[kg ? (CSLOT - 1 - pos) : pos] = c;
        ++pos;
      }
    }
    __syncthreads();
    buf ^= 1;
  }
  counts[(rowW * NCHUNK + cc) * 2 + kg] = pos;
}

// ---------------- K4: finalize (1 wave/row): pos pick + top-10 of collected + loss ----------------
__global__ __launch_bounds__(256) void finalize_kernel(
    const float* __restrict__ feats, const int* __restrict__ labels,
    const float* __restrict__ inv_norm,
    const int* __restrict__ glist, const int* __restrict__ cnt_g,
    const int* __restrict__ counts, const float* __restrict__ vals,
    float* __restrict__ li, int* __restrict__ valid) {
  const int row = blockIdx.x * 4 + (threadIdx.x >> 6);
  const int lane = threadIdx.x & 63;
  const int lab = labels[row];
  const int gc = cnt_g[lab];
  const int gn = gc < GCAP ? gc : GCAP;
  const float4* feats4 = (const float4*)feats;

  // --- positive pick: threefry argmax over same-label (excl self) ---
  uint32_t bk = 0u; int bj = -1;
  for (int e = lane; e < gn; e += 64) {
    int j = glist[lab * GCAP + e];
    if (j != row) {
      uint32_t key = tf_bits((uint32_t)row * (uint32_t)N_ + (uint32_t)j) >> 9;
      if (bj < 0 || key > bk || (key == bk && j < bj)) { bk = key; bj = j; }
    }
  }
#pragma unroll
  for (int o = 32; o; o >>= 1) {
    uint32_t ok = __shfl_xor(bk, o);
    int oj = __shfl_xor(bj, o);
    if (oj >= 0 && (bj < 0 || ok > bk || (ok == bk && oj < bj))) { bk = ok; bj = oj; }
  }

  // --- exact fp32 positive cosine ---
  float pc = 0.f;
  if (bj >= 0) {
    float4 a = feats4[(size_t)row * 64 + lane];
    float4 b = feats4[(size_t)bj * 64 + lane];
    float p = a.x * b.x + a.y * b.y + a.z * b.z + a.w * b.w;
#pragma unroll
    for (int o = 32; o; o >>= 1) p += __shfl_xor(p, o);
    pc = p * inv_norm[row] * inv_norm[bj];
  }

  // --- load collected candidates: 16 cells x 16 slots = 256, 4 per lane (coalesced) ---
  float vv[4];
  int ovf = 0;
#pragma unroll
  for (int q = 0; q < 4; ++q) {
    int s = lane + 64 * q;           // slot id 0..255
    int cell = s >> 4, wi = s & 15;  // chunk cell 0..15
    int c0 = counts[(row * NCHUNK + cell) * 2 + 0];
    int c1 = counts[(row * NCHUNK + cell) * 2 + 1];
    ovf |= (c0 + c1 > CSLOT) ? 1 : 0;
    float val = vals[(size_t)row * (NCHUNK * CSLOT) + s];
    bool live = (wi < c0) || (wi >= CSLOT - (c1 < CSLOT ? c1 : CSLOT));
    vv[q] = live ? val : -INFINITY;
  }

  float num = expf(pc * TEMP_INV);
  float den = num;
  int got = 0;
#pragma unroll 1
  for (int it = 0; it < HARDK; ++it) {
    float lm4 = fmaxf(fmaxf(vv[0], vv[1]), fmaxf(vv[2], vv[3]));
    float wm = lm4;
#pragma unroll
    for (int o = 32; o; o >>= 1) wm = fmaxf(wm, __shfl_xor(wm, o));
    if (wm < -1e37f) break;
    den += expf(wm * TEMP_INV);
    ++got;
    unsigned long long b = __ballot(lm4 == wm);
    int fl = __ffsll((long long)b) - 1;
    if (lane == fl) {
      if (vv[0] == wm) vv[0] = -INFINITY;
      else if (vv[1] == wm) vv[1] = -INFINITY;
      else if (vv[2] == wm) vv[2] = -INFINITY;
      else vv[3] = -INFINITY;
    }
  }

  const int ndiff = N_ - gc;
  const bool vld = (bj >= 0) && (ndiff > 0);
  const int want = ndiff < HARDK ? ndiff : HARDK;

  // --- exact cooperative fallback (P ~ 1e-3 per batch; ~100us if it ever fires) ---
  if (vld && (__any(ovf) || got < want)) {
    float tk[HARDK];
#pragma unroll
    for (int k = 0; k < HARDK; ++k) tk[k] = -INFINITY;
    const float invr = inv_norm[row];
    const float4 a = feats4[(size_t)row * 64 + lane];   // whole row: 64 lanes x float4
#pragma unroll 1
    for (int j = 0; j < N_; ++j) {
      if (j == row || labels[j] == lab) continue;       // wave-uniform branch
      float4 b = feats4[(size_t)j * 64 + lane];
      float p = a.x * b.x + a.y * b.y + a.z * b.z + a.w * b.w;
#pragma unroll
      for (int o = 32; o; o >>= 1) p += __shfl_xor(p, o);
      float c = p * invr * inv_norm[j];                 // wave-uniform value
      if (c > tk[0]) {
        tk[0] = c;
#pragma unroll
        for (int q = 0; q < HARDK - 1; ++q)
          if (tk[q] > tk[q + 1]) { float tmp = tk[q]; tk[q] = tk[q + 1]; tk[q + 1] = tmp; }
      }
    }
    den = num;
#pragma unroll
    for (int k = 0; k < HARDK; ++k)
      if (tk[k] > -1e37f) den += expf(tk[k] * TEMP_INV);
  }

  float L = 0.f;
  if (vld) L = -logf(fmaxf(num / fmaxf(den, 1e-8f), 1e-8f));
  if (lane == 0) {
    li[row] = L;
    valid[row] = vld ? 1 : 0;
  }
}

// ---------------- K5: final mean ----------------
__global__ __launch_bounds__(256) void reduce_kernel(const float* __restrict__ li,
                                                     const int* __restrict__ valid,
                                                     float* __restrict__ out) {
  __shared__ float ssum[4];
  __shared__ int scnt[4];
  float s = 0.f; int c = 0;
  for (int i = threadIdx.x; i < N_; i += 256) { s += li[i]; c += valid[i]; }
#pragma unroll
  for (int o = 32; o; o >>= 1) { s += __shfl_down(s, o); c += __shfl_down(c, o); }
  if ((threadIdx.x & 63) == 0) { ssum[threadIdx.x >> 6] = s; scnt[threadIdx.x >> 6] = c; }
  __syncthreads();
  if (threadIdx.x == 0) {
    float S = 0.f; int C = 0;
    for (int w = 0; w < 4; ++w) { S += ssum[w]; C += scnt[w]; }
    out[0] = S / (float)(C > 0 ? C : 1);
  }
}

extern "C" void kernel_launch(void* const* d_in, const int* in_sizes, int n_in,
                              void* d_out, int out_size, void* d_ws, size_t ws_size,
                              hipStream_t stream) {
  const float* feats  = (const float*)d_in[0];
  const int*   labels = (const int*)d_in[1];
  float* out = (float*)d_out;

  char* w = (char*)d_ws;
  unsigned short* zbf = (unsigned short*)w;  w += (size_t)N_ * D_ * 2;        // 4 MB
  float* inv_norm = (float*)w;               w += (size_t)N_ * 4;
  uint32_t* mask_g = (uint32_t*)w;           w += (size_t)NLBL * 256 * 4;     // 128 KB
  int* glist = (int*)w;                      w += (size_t)NLBL * GCAP * 4;    // 128 KB
  int* cnt_g = (int*)w;                      w += (size_t)NLBL * 4;
  int* counts = (int*)w;                     w += (size_t)N_ * NCHUNK * 2 * 4;        // 1 MB
  float* vals = (float*)w;                   w += (size_t)N_ * NCHUNK * CSLOT * 4;    // 8.4 MB
  float* li_arr = (float*)w;                 w += (size_t)N_ * 4;
  int* valid_arr = (int*)w;                  w += (size_t)N_ * 4;

  hipLaunchKernelGGL(prep_kernel, dim3(N_ / 4), dim3(256), 0, stream, feats, inv_norm, zbf);
  hipLaunchKernelGGL(group_kernel, dim3(NLBL), dim3(256), 0, stream, labels, mask_g, glist, cnt_g);
  hipLaunchKernelGGL(collect_kernel, dim3(64 * NCHUNK), dim3(256), 0, stream,
                     zbf, labels, mask_g, vals, counts);
  hipLaunchKernelGGL(finalize_kernel, dim3(N_ / 4), dim3(256), 0, stream,
                     feats, labels, inv_norm, glist, cnt_g, counts, vals, li_arr, valid_arr);
  hipLaunchKernelGGL(reduce_kernel, dim3(1), dim3(256), 0, stream, li_arr, valid_arr, out);
}

// Round 7
// 94.455 us; speedup vs baseline: 8.1595x; 1.0076x over previous
//
#include <hip/hip_runtime.h>
#include <cstdint>
#include <math.h>

#define N_     8192
#define D_     256
#define NLBL   128
#define TEMP_INV 14.285714285714286f
#define HARDK  10
#define THETA  0.16f
#define GCAP   256              // per-label list capacity (mean 64, max ~104)

#define RB     256              // rows per block (4 waves x 2 rowgroups x 32)
#define NCHUNK 16
#define CHUNK  (N_ / NCHUNK)    // 512 cols per block
#define TILES  (CHUNK / 32)     // 16
#define CSLOT  16               // per-(row,chunk) capacity, kg0 front / kg1 back

typedef __attribute__((ext_vector_type(8)))  short bf16x8;
typedef __attribute__((ext_vector_type(16))) float f32x16;

// ---------------- Threefry-2x32, key=(0,42): exact-match validated R1-R6 ----------------
__device__ __forceinline__ uint32_t rotl32(uint32_t x, int n) {
  return (x << n) | (x >> (32 - n));
}
__device__ uint32_t tf_bits(uint32_t idx) {
  uint32_t x0 = 0u, x1 = idx;
  const uint32_t k0 = 0u, k1 = 42u;
  const uint32_t k2 = k0 ^ k1 ^ 0x1BD11BDAu;
  x0 += k0; x1 += k1;
#define TFR(r) { x0 += x1; x1 = rotl32(x1, r); x1 ^= x0; }
  TFR(13) TFR(15) TFR(26) TFR(6)
  x0 += k1; x1 += k2 + 1u;
  TFR(17) TFR(29) TFR(16) TFR(24)
  x0 += k2; x1 += k0 + 2u;
  TFR(13) TFR(15) TFR(26) TFR(6)
  x0 += k0; x1 += k1 + 3u;
  TFR(17) TFR(29) TFR(16) TFR(24)
  x0 += k1; x1 += k2 + 4u;
  TFR(13) TFR(15) TFR(26) TFR(6)
  x0 += k2; x1 += k0 + 5u;
#undef TFR
  return x0 ^ x1;
}

__device__ __forceinline__ unsigned short f2bf(float x) {  // RNE
  uint32_t b = __float_as_uint(x);
  return (unsigned short)((b + 0x7FFFu + ((b >> 16) & 1u)) >> 16);
}

// ---------------- K1: inv_norm + bf16 z (4 rows/block) ----------------
__global__ __launch_bounds__(256) void prep_kernel(const float* __restrict__ feats,
                                                   float* __restrict__ inv_norm,
                                                   unsigned short* __restrict__ zbf) {
  const int i = blockIdx.x * 4 + (threadIdx.x >> 6);
  const int l = threadIdx.x & 63;
  float4 v = ((const float4*)feats)[(size_t)i * 64 + l];
  float ss = v.x * v.x + v.y * v.y + v.z * v.z + v.w * v.w;
#pragma unroll
  for (int o = 32; o; o >>= 1) ss += __shfl_xor(ss, o);
  float inv = 1.0f / fmaxf(sqrtf(ss), 1e-12f);
  if (l == 0) inv_norm[i] = inv;
  uint2 p;
  p.x = (uint32_t)f2bf(v.x * inv) | ((uint32_t)f2bf(v.y * inv) << 16);
  p.y = (uint32_t)f2bf(v.z * inv) | ((uint32_t)f2bf(v.w * inv) << 16);
  ((uint2*)zbf)[(size_t)i * 64 + l] = p;
}

// ---------------- K2: per-label bitmask + member list ----------------
__global__ __launch_bounds__(256) void group_kernel(const int* __restrict__ labels,
                                                    uint32_t* __restrict__ mask_g,
                                                    int* __restrict__ glist,
                                                    int* __restrict__ cnt_g) {
  const int b = blockIdx.x;
  const int tid = threadIdx.x, lane = tid & 63, wv = tid >> 6;
  __shared__ int lcnt;
  if (tid == 0) lcnt = 0;
  __syncthreads();
  for (int it = 0; it < N_; it += 256) {
    int col = it + tid;
    bool pred = (labels[col] == b);
    unsigned long long m = __ballot(pred);
    if (lane == 0) {
      int w0 = (it + wv * 64) >> 5;
      mask_g[b * 256 + w0]     = (uint32_t)m;
      mask_g[b * 256 + w0 + 1] = (uint32_t)(m >> 32);
    }
    if (pred) {
      int p = atomicAdd(&lcnt, 1);
      if (p < GCAP) glist[b * GCAP + p] = col;
    }
  }
  __syncthreads();
  if (tid == 0) cnt_g[b] = lcnt;
}

// ---------------- K3: MFMA sim (2 rowgroups/wave) + threshold collect ----------------
__device__ __forceinline__ void stage_tile(const unsigned short* zbf, char (*AbK)[1024],
                                           int colT, int wid, int l, int kg) {
  const char* base = (const char*)zbf + ((size_t)(colT + (l & 31)) * (D_ * 2) + kg * 16);
#pragma unroll
  for (int q = 0; q < 4; ++q) {
    const int kk = wid * 4 + q;
    __builtin_amdgcn_global_load_lds(
        (const __attribute__((address_space(1))) void*)(base + kk * 32),
        (__attribute__((address_space(3))) void*)(&AbK[kk][0]), 16, 0, 0);
  }
}

__global__ __launch_bounds__(256, 2) void collect_kernel(const unsigned short* __restrict__ zbf,
                                                         const int* __restrict__ labels,
                                                         const uint32_t* __restrict__ mask_g,
                                                         float* __restrict__ vals,
                                                         int* __restrict__ counts) {
  __shared__ char Ab[2][16][1024];  // [buf][kk][lane*16]

  const int tid = threadIdx.x;
  const int l = tid & 63, wid = tid >> 6;
  const int kg = l >> 5;
  const int bx = blockIdx.x;
  const int rc = bx & 31, cc = bx >> 5;
  const int row0 = rc * RB;
  const int col0 = cc * CHUNK;
  const int rowA = row0 + wid * 64 + (l & 31);   // rowgroup A
  const int rowB = rowA + 32;                    // rowgroup B
  const int labA = labels[rowA];
  const int labB = labels[rowB];
  const uint32_t* mrowA = mask_g + labA * 256 + (col0 >> 5);
  const uint32_t* mrowB = mask_g + labB * 256 + (col0 >> 5);

  // B fragments for both rowgroups: 2 x 16 K-steps (128 VGPRs)
  bf16x8 bfA[16], bfB[16];
  {
    const bf16x8* zrA = (const bf16x8*)(zbf + (size_t)rowA * D_);
    const bf16x8* zrB = (const bf16x8*)(zbf + (size_t)rowB * D_);
#pragma unroll
    for (int kk = 0; kk < 16; ++kk) {
      bfA[kk] = zrA[kk * 2 + kg];
      bfB[kk] = zrB[kk * 2 + kg];
    }
  }

  // Shared 16-slot cell per (row, chunk); kg=0 fills front, kg=1 back.
  float* vbA = vals + (size_t)rowA * (NCHUNK * CSLOT) + cc * CSLOT;
  float* vbB = vals + (size_t)rowB * (NCHUNK * CSLOT) + cc * CSLOT;
  int posA = 0, posB = 0;

  stage_tile(zbf, Ab[0], col0, wid, l, kg);
  __syncthreads();

  int buf = 0;
  for (int t = 0; t < TILES; ++t) {
    if (t + 1 < TILES) stage_tile(zbf, Ab[buf ^ 1], col0 + (t + 1) * 32, wid, l, kg);
    const uint32_t wshA = mrowA[t] >> (kg * 4);
    const uint32_t wshB = mrowB[t] >> (kg * 4);

    f32x16 accA, accB;
#pragma unroll
    for (int r = 0; r < 16; ++r) { accA[r] = 0.f; accB[r] = 0.f; }
#pragma unroll
    for (int kk = 0; kk < 16; ++kk) {
      bf16x8 a = *(const bf16x8*)&Ab[buf][kk][l * 16];   // one LDS read ...
      accA = __builtin_amdgcn_mfma_f32_32x32x16_bf16(a, bfA[kk], accA, 0, 0, 0);  // ... feeds
      accB = __builtin_amdgcn_mfma_f32_32x32x16_bf16(a, bfB[kk], accB, 0, 0, 0);  // ... 2 MFMAs
    }

    // scan both rowgroups; acc[r] = sim(row, col0 + t*32 + cpos + 4*kg)
#pragma unroll
    for (int r = 0; r < 16; ++r) {
      const int cpos = (r & 3) + 8 * (r >> 2);
      float cA = accA[r];
      if ((((wshA >> cpos) & 1u) == 0u) && (cA > THETA)) {
        if (posA < CSLOT) vbA[kg ? (CSLOT - 1 - posA) : posA] = cA;
        ++posA;
      }
      float cB = accB[r];
      if ((((wshB >> cpos) & 1u) == 0u) && (cB > THETA)) {
        if (posB < CSLOT) vbB[kg ? (CSLOT - 1 - posB) : posB] = cB;
        ++posB;
      }
    }
    __syncthreads();
    buf ^= 1;
  }
  counts[(rowA * NCHUNK + cc) * 2 + kg] = posA;
  counts[(rowB * NCHUNK + cc) * 2 + kg] = posB;
}

// ---------------- K4: finalize (1 wave/row): pos pick + top-10 of collected + loss ----------------
__global__ __launch_bounds__(256) void finalize_kernel(
    const float* __restrict__ feats, const int* __restrict__ labels,
    const float* __restrict__ inv_norm,
    const int* __restrict__ glist, const int* __restrict__ cnt_g,
    const int* __restrict__ counts, const float* __restrict__ vals,
    float* __restrict__ li, int* __restrict__ valid) {
  const int row = blockIdx.x * 4 + (threadIdx.x >> 6);
  const int lane = threadIdx.x & 63;
  const int lab = labels[row];
  const int gc = cnt_g[lab];
  const int gn = gc < GCAP ? gc : GCAP;
  const float4* feats4 = (const float4*)feats;

  // --- positive pick: threefry argmax over same-label (excl self) ---
  uint32_t bk = 0u; int bj = -1;
  for (int e = lane; e < gn; e += 64) {
    int j = glist[lab * GCAP + e];
    if (j != row) {
      uint32_t key = tf_bits((uint32_t)row * (uint32_t)N_ + (uint32_t)j) >> 9;
      if (bj < 0 || key > bk || (key == bk && j < bj)) { bk = key; bj = j; }
    }
  }
#pragma unroll
  for (int o = 32; o; o >>= 1) {
    uint32_t ok = __shfl_xor(bk, o);
    int oj = __shfl_xor(bj, o);
    if (oj >= 0 && (bj < 0 || ok > bk || (ok == bk && oj < bj))) { bk = ok; bj = oj; }
  }

  // --- exact fp32 positive cosine ---
  float pc = 0.f;
  if (bj >= 0) {
    float4 a = feats4[(size_t)row * 64 + lane];
    float4 b = feats4[(size_t)bj * 64 + lane];
    float p = a.x * b.x + a.y * b.y + a.z * b.z + a.w * b.w;
#pragma unroll
    for (int o = 32; o; o >>= 1) p += __shfl_xor(p, o);
    pc = p * inv_norm[row] * inv_norm[bj];
  }

  // --- load collected candidates: 16 cells x 16 slots = 256, 4 per lane (coalesced) ---
  float vv[4];
  int ovf = 0;
#pragma unroll
  for (int q = 0; q < 4; ++q) {
    int s = lane + 64 * q;           // slot id 0..255
    int cell = s >> 4, wi = s & 15;  // chunk cell 0..15
    int c0 = counts[(row * NCHUNK + cell) * 2 + 0];
    int c1 = counts[(row * NCHUNK + cell) * 2 + 1];
    ovf |= (c0 + c1 > CSLOT) ? 1 : 0;
    float val = vals[(size_t)row * (NCHUNK * CSLOT) + s];
    bool live = (wi < c0) || (wi >= CSLOT - (c1 < CSLOT ? c1 : CSLOT));
    vv[q] = live ? val : -INFINITY;
  }

  float num = expf(pc * TEMP_INV);
  float den = num;
  int got = 0;
#pragma unroll 1
  for (int it = 0; it < HARDK; ++it) {
    float lm4 = fmaxf(fmaxf(vv[0], vv[1]), fmaxf(vv[2], vv[3]));
    float wm = lm4;
#pragma unroll
    for (int o = 32; o; o >>= 1) wm = fmaxf(wm, __shfl_xor(wm, o));
    if (wm < -1e37f) break;
    den += expf(wm * TEMP_INV);
    ++got;
    unsigned long long b = __ballot(lm4 == wm);
    int fl = __ffsll((long long)b) - 1;
    if (lane == fl) {
      if (vv[0] == wm) vv[0] = -INFINITY;
      else if (vv[1] == wm) vv[1] = -INFINITY;
      else if (vv[2] == wm) vv[2] = -INFINITY;
      else vv[3] = -INFINITY;
    }
  }

  const int ndiff = N_ - gc;
  const bool vld = (bj >= 0) && (ndiff > 0);
  const int want = ndiff < HARDK ? ndiff : HARDK;

  // --- exact cooperative fallback (P ~ 1e-3 per batch; ~100us if it ever fires) ---
  if (vld && (__any(ovf) || got < want)) {
    float tk[HARDK];
#pragma unroll
    for (int k = 0; k < HARDK; ++k) tk[k] = -INFINITY;
    const float invr = inv_norm[row];
    const float4 a = feats4[(size_t)row * 64 + lane];   // whole row: 64 lanes x float4
#pragma unroll 1
    for (int j = 0; j < N_; ++j) {
      if (j == row || labels[j] == lab) continue;       // wave-uniform branch
      float4 b = feats4[(size_t)j * 64 + lane];
      float p = a.x * b.x + a.y * b.y + a.z * b.z + a.w * b.w;
#pragma unroll
      for (int o = 32; o; o >>= 1) p += __shfl_xor(p, o);
      float c = p * invr * inv_norm[j];                 // wave-uniform value
      if (c > tk[0]) {
        tk[0] = c;
#pragma unroll
        for (int q = 0; q < HARDK - 1; ++q)
          if (tk[q] > tk[q + 1]) { float tmp = tk[q]; tk[q] = tk[q + 1]; tk[q + 1] = tmp; }
      }
    }
    den = num;
#pragma unroll
    for (int k = 0; k < HARDK; ++k)
      if (tk[k] > -1e37f) den += expf(tk[k] * TEMP_INV);
  }

  float L = 0.f;
  if (vld) L = -logf(fmaxf(num / fmaxf(den, 1e-8f), 1e-8f));
  if (lane == 0) {
    li[row] = L;
    valid[row] = vld ? 1 : 0;
  }
}

// ---------------- K5: final mean ----------------
__global__ __launch_bounds__(256) void reduce_kernel(const float* __restrict__ li,
                                                     const int* __restrict__ valid,
                                                     float* __restrict__ out) {
  __shared__ float ssum[4];
  __shared__ int scnt[4];
  float s = 0.f; int c = 0;
  for (int i = threadIdx.x; i < N_; i += 256) { s += li[i]; c += valid[i]; }
#pragma unroll
  for (int o = 32; o; o >>= 1) { s += __shfl_down(s, o); c += __shfl_down(c, o); }
  if ((threadIdx.x & 63) == 0) { ssum[threadIdx.x >> 6] = s; scnt[threadIdx.x >> 6] = c; }
  __syncthreads();
  if (threadIdx.x == 0) {
    float S = 0.f; int C = 0;
    for (int w = 0; w < 4; ++w) { S += ssum[w]; C += scnt[w]; }
    out[0] = S / (float)(C > 0 ? C : 1);
  }
}

extern "C" void kernel_launch(void* const* d_in, const int* in_sizes, int n_in,
                              void* d_out, int out_size, void* d_ws, size_t ws_size,
                              hipStream_t stream) {
  const float* feats  = (const float*)d_in[0];
  const int*   labels = (const int*)d_in[1];
  float* out = (float*)d_out;

  char* w = (char*)d_ws;
  unsigned short* zbf = (unsigned short*)w;  w += (size_t)N_ * D_ * 2;        // 4 MB
  float* inv_norm = (float*)w;               w += (size_t)N_ * 4;
  uint32_t* mask_g = (uint32_t*)w;           w += (size_t)NLBL * 256 * 4;     // 128 KB
  int* glist = (int*)w;                      w += (size_t)NLBL * GCAP * 4;    // 128 KB
  int* cnt_g = (int*)w;                      w += (size_t)NLBL * 4;
  int* counts = (int*)w;                     w += (size_t)N_ * NCHUNK * 2 * 4;        // 1 MB
  float* vals = (float*)w;                   w += (size_t)N_ * NCHUNK * CSLOT * 4;    // 8.4 MB
  float* li_arr = (float*)w;                 w += (size_t)N_ * 4;
  int* valid_arr = (int*)w;                  w += (size_t)N_ * 4;

  hipLaunchKernelGGL(prep_kernel, dim3(N_ / 4), dim3(256), 0, stream, feats, inv_norm, zbf);
  hipLaunchKernelGGL(group_kernel, dim3(NLBL), dim3(256), 0, stream, labels, mask_g, glist, cnt_g);
  hipLaunchKernelGGL(collect_kernel, dim3(32 * NCHUNK), dim3(256), 0, stream,
                     zbf, labels, mask_g, vals, counts);
  hipLaunchKernelGGL(finalize_kernel, dim3(N_ / 4), dim3(256), 0, stream,
                     feats, labels, inv_norm, glist, cnt_g, counts, vals, li_arr, valid_arr);
  hipLaunchKernelGGL(reduce_kernel, dim3(1), dim3(256), 0, stream, li_arr, valid_arr, out);
}